// Round 10
// baseline (253.675 us; speedup 1.0000x reference)
//
#include <hip/hip_runtime.h>

// Laplacian-kernel regression, fused, bf16 MFMA 16x16x32.
//   d2 = ||x||^2 + ||z||^2 - 2 X.Z^T ; P = exp(-sqrt(d2)/10) ; out = P @ W
// R10 = R9 structure (X K-halves in LDS, Z/W direct fragment loads, 4
// barriers/m-tile, grid (64,4), 512 thr, wave grid 2x4, 4x4 frags) plus:
//   - transform VALU diet: rsq-based sqrt, amdgcn_exp2, trunc-bf16
//   - double-buffered register prefetch of Z (kk+1) and W (pv+1) fragments;
//     next-phase loads issued BEFORE barriers to overlap the drain
//   - 32-bit voffset addressing for Zf/Wf
// Occupancy is locked at 2 waves/SIMD by the 128-reg accumulator footprint;
// this round attacks VALU time + exposed load latency instead.

using frag8 = __attribute__((ext_vector_type(8))) short;   // 8 bf16 (4 VGPRs)
using f32x4 = __attribute__((ext_vector_type(4))) float;   // 16x16 C/D frag

constexpr int Nn = 8192, Mm = 8192, Dd = 512, Yd = 256;
constexpr int BM = 128, BN = 256;
constexpr int MCH = 4, MPER = Mm / MCH, MT = MPER / BN;    // 2048, 8
constexpr int LDP = BN + 8;    // 264 ushort rows (528 B, 16B-aligned)

// Fragment-tile layout: frag(g, c) = rows [16g,16g+16) x k [32c,32c+32),
// 512 ushorts at (g*KG + c)*512, element (r,k) at ushort lane*8 + k%8 where
// lane = r%16 + 16*((k%32)/8).  Xf/Zf: KG=16 (K=512). Wf: rows=y, KG=256.

// workspace layout (bytes)
constexpr size_t OFF_XF  = 0;                               // 8 MB
constexpr size_t OFF_ZF  = OFF_XF + (size_t)Nn * Dd * 2;    // 8 MB
constexpr size_t OFF_WF  = OFF_ZF + (size_t)Mm * Dd * 2;    // 4 MB
constexpr size_t OFF_XSQ = OFF_WF + (size_t)Yd * Mm * 2;
constexpr size_t OFF_ZSQ = OFF_XSQ + (size_t)Nn * 4;
constexpr size_t WS_NEED = OFF_ZSQ + (size_t)Mm * 4;        // ~20.1 MB

__device__ __forceinline__ ushort f2bf(float f) {
    unsigned u = __builtin_bit_cast(unsigned, f);
    u += 0x7FFFu + ((u >> 16) & 1u);          // RNE (prep only)
    return (ushort)(u >> 16);
}

// ---- prep (LDS-tiled, coalesced; norm phase stride-517 = 4-way max) ----
__global__ __launch_bounds__(256) void prep_v10(
    const float* __restrict__ X, const float* __restrict__ Z,
    const float* __restrict__ W, ushort* __restrict__ Xf,
    ushort* __restrict__ Zf, ushort* __restrict__ Wf,
    float* __restrict__ xsq, float* __restrict__ zsq)
{
    __shared__ float tile[8320];                  // 16x517 (X/Z) or 32x260 (W)
    __shared__ float part[256];
    const int t = threadIdx.x, b = blockIdx.x;
    if (b < 1024) {
        const int g = (b < 512) ? b : b - 512;
        const float* src = (b < 512 ? X : Z) + (size_t)g * 16 * Dd;
        ushort* dst = (b < 512 ? Xf : Zf) + (size_t)g * 16 * 512;
        float* nrm = (b < 512 ? xsq : zsq) + g * 16;
        #pragma unroll
        for (int rep = 0; rep < 8; ++rep) {       // 2048 float4, coalesced
            const int idx = rep * 256 + t;
            const int r = idx >> 7, c4 = (idx & 127) * 4;
            const float4 v = *(const float4*)(src + (size_t)r * Dd + c4);
            float* d = tile + r * 517 + c4;
            d[0] = v.x; d[1] = v.y; d[2] = v.z; d[3] = v.w;
        }
        __syncthreads();
        {   // norms: row r = t&15 (bank-spread), segment t>>4
            const int r = t & 15, s0 = (t >> 4) * 32;
            float sq = 0.0f;
            #pragma unroll
            for (int k = 0; k < 32; ++k) {
                const float v = tile[r * 517 + s0 + k];
                sq += v * v;
            }
            part[t] = sq;
        }
        __syncthreads();
        if (t < 16) {
            float sq = 0.0f;
            #pragma unroll
            for (int s = 0; s < 16; ++s) sq += part[t + 16 * s];
            nrm[t] = sq;
        }
        #pragma unroll
        for (int rep = 0; rep < 4; ++rep) {       // 1024 uint4 frag writes
            const int idx = rep * 256 + t;
            const int kg = idx >> 6, w = idx & 63;
            const int l16 = w & 15, quad = w >> 4;
            const float* s = tile + l16 * 517 + kg * 32 + quad * 8;
            uint4 pk;
            pk.x = (unsigned)f2bf(s[0]) | ((unsigned)f2bf(s[1]) << 16);
            pk.y = (unsigned)f2bf(s[2]) | ((unsigned)f2bf(s[3]) << 16);
            pk.z = (unsigned)f2bf(s[4]) | ((unsigned)f2bf(s[5]) << 16);
            pk.w = (unsigned)f2bf(s[6]) | ((unsigned)f2bf(s[7]) << 16);
            *(uint4*)(dst + (size_t)kg * 512 + w * 8) = pk;
        }
    } else {
        const int zg = b - 1024;                  // 32-z stripe of W
        const float* src = W + (size_t)zg * 32 * Yd;
        #pragma unroll
        for (int rep = 0; rep < 8; ++rep) {
            const int idx = rep * 256 + t;
            const int r = idx >> 6, c4 = (idx & 63) * 4;
            const float4 v = *(const float4*)(src + (size_t)r * Yd + c4);
            float* d = tile + r * 260 + c4;
            d[0] = v.x; d[1] = v.y; d[2] = v.z; d[3] = v.w;
        }
        __syncthreads();
        #pragma unroll
        for (int rep = 0; rep < 4; ++rep) {
            const int idx = rep * 256 + t;
            const int yg = idx >> 6, w = idx & 63;
            const int l16 = w & 15, quad = w >> 4;
            const int y = yg * 16 + l16;
            ushort rr[8];
            #pragma unroll
            for (int j = 0; j < 8; ++j)
                rr[j] = f2bf(tile[(quad * 8 + j) * 260 + y]);
            uint4 pk;
            pk.x = (unsigned)rr[0] | ((unsigned)rr[1] << 16);
            pk.y = (unsigned)rr[2] | ((unsigned)rr[3] << 16);
            pk.z = (unsigned)rr[4] | ((unsigned)rr[5] << 16);
            pk.w = (unsigned)rr[6] | ((unsigned)rr[7] << 16);
            *(uint4*)(Wf + ((size_t)yg * 256 + zg) * 512 + w * 8) = pk;
        }
    }
}

// ---- main fused kernel ----
__global__ __launch_bounds__(512, 2) void laplace_v10(
    const ushort* __restrict__ Xf, const ushort* __restrict__ Zf,
    const ushort* __restrict__ Wf, const float* __restrict__ xsqg,
    const float* __restrict__ zsqg, float* __restrict__ O)
{
    __shared__ ushort sXh[64 * 512];              // 64 KB: X K-half, 64 frags
    __shared__ ushort sP[BM * LDP];               // 67.6 KB
    const int t = threadIdx.x, wid = t >> 6, lane = t & 63;
    const int l16 = lane & 15, quad = lane >> 4;
    const int wr = wid >> 2, wc = wid & 3;        // wave grid 2x4
    const int row0  = blockIdx.x * BM;            // XCD = blockIdx.x % 8
    const int zbase = blockIdx.y * MPER;
    const int xg0 = row0 >> 4;

    float xs[4][4];
    #pragma unroll
    for (int i = 0; i < 4; ++i)
        #pragma unroll
        for (int r = 0; r < 4; ++r)
            xs[i][r] = xsqg[row0 + wr * 64 + 16 * i + quad * 4 + r];

    f32x4 Oa[4][4];
    #pragma unroll
    for (int i = 0; i < 4; ++i)
        #pragma unroll
        for (int j = 0; j < 4; ++j)
            #pragma unroll
            for (int r = 0; r < 4; ++r) Oa[i][j][r] = 0.0f;

    // staging source/dest (wave-contiguous 1 KB copies)
    const ushort* xsrc0 = Xf + ((size_t)xg0 * 16 + wid) * 512 + lane * 8;
    ushort* xdst = sXh + wid * 512 + lane * 8;

    for (int mt = 0; mt < MT; ++mt) {
        const int zg0 = (zbase >> 4) + mt * 16;
        float zs4[4];
        #pragma unroll
        for (int j = 0; j < 4; ++j)
            zs4[j] = zsqg[zbase + mt * 256 + wc * 64 + 16 * j + l16];

        f32x4 S[4][4];
        #pragma unroll
        for (int i = 0; i < 4; ++i)
            #pragma unroll
            for (int j = 0; j < 4; ++j)
                #pragma unroll
                for (int r = 0; r < 4; ++r) S[i][j][r] = 0.0f;

        const unsigned zo0 = (unsigned)(zg0 + wc * 4) * 8192u + lane * 8;

        // ---- QK in two K-halves; X from LDS, Z direct (double-buffered) ----
        #pragma unroll
        for (int h = 0; h < 2; ++h) {
            // stage sXh (8 x 1KB per wave); prev readers done per barrier chain
            #pragma unroll
            for (int rep = 0; rep < 8; ++rep)
                *(uint4*)(xdst + rep * 4096) =
                    *(const uint4*)(xsrc0 + (size_t)(rep * 16 + h * 8) * 512);
            // prefetch kk=0 Z frags BEFORE the barrier (overlaps drain)
            const unsigned zoh = zo0 + h * 4096u;
            frag8 bA[4], bB[4];
            #pragma unroll
            for (int j = 0; j < 4; ++j)
                bA[j] = *(const frag8*)(Zf + zoh + j * 8192u);
            __syncthreads();                      // sXh ready
            #pragma unroll
            for (int kk = 0; kk < 8; ++kk) {
                if (kk + 1 < 8) {                 // prefetch kk+1
                    const unsigned zo2 = zoh + (unsigned)(kk + 1) * 512u;
                    if ((kk & 1) == 0) {
                        #pragma unroll
                        for (int j = 0; j < 4; ++j)
                            bB[j] = *(const frag8*)(Zf + zo2 + j * 8192u);
                    } else {
                        #pragma unroll
                        for (int j = 0; j < 4; ++j)
                            bA[j] = *(const frag8*)(Zf + zo2 + j * 8192u);
                    }
                }
                frag8 a[4];
                #pragma unroll
                for (int i = 0; i < 4; ++i)
                    a[i] = *(const frag8*)(sXh + ((wr * 4 + i) * 8 + kk) * 512 + lane * 8);
                if ((kk & 1) == 0) {
                    #pragma unroll
                    for (int i = 0; i < 4; ++i)
                        #pragma unroll
                        for (int j = 0; j < 4; ++j)
                            S[i][j] = __builtin_amdgcn_mfma_f32_16x16x32_bf16(
                                a[i], bA[j], S[i][j], 0, 0, 0);
                } else {
                    #pragma unroll
                    for (int i = 0; i < 4; ++i)
                        #pragma unroll
                        for (int j = 0; j < 4; ++j)
                            S[i][j] = __builtin_amdgcn_mfma_f32_16x16x32_bf16(
                                a[i], bB[j], S[i][j], 0, 0, 0);
                }
            }
            if (h == 0) __syncthreads();          // all QK-h0 sXh reads done
        }

        // ---- transform -> sP (C/D: col=l16, row=quad*4+r); cheap path:
        //      sqrt via rsq (d2>=1e-20 guard), exp via v_exp, trunc bf16 ----
        #pragma unroll
        for (int i = 0; i < 4; ++i) {
            const int xl = wr * 64 + 16 * i + quad * 4;
            #pragma unroll
            for (int j = 0; j < 4; ++j) {
                const int col = wc * 64 + 16 * j + l16;
                const float zz = zs4[j];
                #pragma unroll
                for (int r = 0; r < 4; ++r) {
                    const float xpz = xs[i][r] + zz;
                    float d2 = fmaf(S[i][j][r], -2.0f, xpz);
                    d2 = fmaxf(d2, 1e-20f);
                    const float dist = d2 * __frsqrt_rn(d2);     // sqrt(d2)
                    const float e = __builtin_amdgcn_exp2f(
                        dist * -0.14426950408889634f);           // exp(-dist/10)
                    sP[(xl + r) * LDP + col] =
                        (ushort)(__builtin_bit_cast(unsigned, e) >> 16);
                }
            }
        }
        // prefetch pv=0 W frags BEFORE the barrier
        const unsigned wo0 = (unsigned)(wc * 4) * 131072u +
                             (unsigned)((zbase >> 5) + mt * 8) * 512u + lane * 8;
        frag8 wA[4], wB[4];
        #pragma unroll
        for (int j = 0; j < 4; ++j)
            wA[j] = *(const frag8*)(Wf + wo0 + j * 131072u);
        __syncthreads();                          // sP visible

        // ---- PV: O += P[128x256].W[256x256]; A from sP, B direct ----
        #pragma unroll
        for (int pv = 0; pv < 8; ++pv) {
            if (pv + 1 < 8) {
                const unsigned wo2 = wo0 + (unsigned)(pv + 1) * 512u;
                if ((pv & 1) == 0) {
                    #pragma unroll
                    for (int j = 0; j < 4; ++j)
                        wB[j] = *(const frag8*)(Wf + wo2 + j * 131072u);
                } else {
                    #pragma unroll
                    for (int j = 0; j < 4; ++j)
                        wA[j] = *(const frag8*)(Wf + wo2 + j * 131072u);
                }
            }
            frag8 ap[4];
            #pragma unroll
            for (int i = 0; i < 4; ++i)
                ap[i] = *(const frag8*)(
                    sP + (wr * 64 + 16 * i + l16) * LDP + pv * 32 + quad * 8);
            if ((pv & 1) == 0) {
                #pragma unroll
                for (int j = 0; j < 4; ++j)
                    #pragma unroll
                    for (int i = 0; i < 4; ++i)
                        Oa[i][j] = __builtin_amdgcn_mfma_f32_16x16x32_bf16(
                            ap[i], wA[j], Oa[i][j], 0, 0, 0);
            } else {
                #pragma unroll
                for (int j = 0; j < 4; ++j)
                    #pragma unroll
                    for (int i = 0; i < 4; ++i)
                        Oa[i][j] = __builtin_amdgcn_mfma_f32_16x16x32_bf16(
                            ap[i], wB[j], Oa[i][j], 0, 0, 0);
            }
        }
        // next mt stage-h0 safe: sP barrier above implies QK-h1 reads done.
    }

    // ---- epilogue: combine MCH=4 chunks via fp32 atomics (XCD-local) ----
    #pragma unroll
    for (int i = 0; i < 4; ++i) {
        const int xr = row0 + wr * 64 + 16 * i + quad * 4;
        #pragma unroll
        for (int j = 0; j < 4; ++j) {
            const int col = wc * 64 + 16 * j + l16;
            #pragma unroll
            for (int r = 0; r < 4; ++r)
                atomicAdd(&O[(size_t)(xr + r) * Yd + col], Oa[i][j][r]);
        }
    }
}

// ---- fallback (fp32 VALU fused kernel) if workspace is too small ----
constexpr int FBM = 64, FBN = 64, FBK = 64;
constexpr int FMCH = 4, FMCHUNK = Mm / FMCH, FMSTEPS = FMCHUNK / FBN, FDSTEPS = Dd / FBK;
constexpr int FLDA = FBK + 1, FLDSS = FBN + 1;

__global__ __launch_bounds__(256, 3) void laplace_fused_v1(
    const float* __restrict__ X, const float* __restrict__ Z,
    const float* __restrict__ W, float* __restrict__ O)
{
    __shared__ float sX[FBM * FLDA];
    __shared__ float sZ[FBN * FLDA];
    __shared__ float sS[FBM * FLDSS];
    const int t = threadIdx.x, pr = t >> 4, pc = t & 15, sc4 = pc * 4;
    const int row0 = blockIdx.x * FBM, mbase = blockIdx.y * FMCHUNK;
    float o[4][4][4];
    #pragma unroll
    for (int i = 0; i < 4; ++i)
        for (int yb = 0; yb < 4; ++yb)
            for (int j = 0; j < 4; ++j) o[i][yb][j] = 0.0f;
    for (int ms = 0; ms < FMSTEPS; ++ms) {
        const int zrow0 = mbase + ms * FBN;
        float s[4][4];
        #pragma unroll
        for (int i = 0; i < 4; ++i)
            for (int j = 0; j < 4; ++j) s[i][j] = 0.0f;
        for (int kk = 0; kk < FDSTEPS; ++kk) {
            const int k0 = kk * FBK;
            __syncthreads();
            #pragma unroll
            for (int rep = 0; rep < 4; ++rep) {
                const int r = pr + rep * 16;
                const float4 xv = *reinterpret_cast<const float4*>(X + (size_t)(row0 + r) * Dd + k0 + sc4);
                const float4 zv = *reinterpret_cast<const float4*>(Z + (size_t)(zrow0 + r) * Dd + k0 + sc4);
                float* dx = sX + r * FLDA + sc4;
                dx[0] = xv.x; dx[1] = xv.y; dx[2] = xv.z; dx[3] = xv.w;
                float* dz = sZ + r * FLDA + sc4;
                dz[0] = zv.x; dz[1] = zv.y; dz[2] = zv.z; dz[3] = zv.w;
            }
            __syncthreads();
            #pragma unroll 4
            for (int k = 0; k < FBK; ++k) {
                float xr[4], zc[4];
                #pragma unroll
                for (int i = 0; i < 4; ++i) xr[i] = sX[(pr * 4 + i) * FLDA + k];
                #pragma unroll
                for (int j = 0; j < 4; ++j) zc[j] = sZ[(pc * 4 + j) * FLDA + k];
                #pragma unroll
                for (int i = 0; i < 4; ++i)
                    #pragma unroll
                    for (int j = 0; j < 4; ++j) {
                        const float d = xr[i] - zc[j];
                        s[i][j] = fmaf(d, d, s[i][j]);
                    }
            }
        }
        #pragma unroll
        for (int i = 0; i < 4; ++i)
            for (int j = 0; j < 4; ++j)
                sS[(pr * 4 + i) * FLDSS + sc4 + j] = __expf(-sqrtf(s[i][j]) * 0.1f);
        __syncthreads();
        #pragma unroll 2
        for (int c = 0; c < FBN; ++c) {
            float sv[4];
            #pragma unroll
            for (int i = 0; i < 4; ++i) sv[i] = sS[(pr * 4 + i) * FLDSS + c];
            const float* wrow = W + (size_t)(zrow0 + c) * Yd;
            #pragma unroll
            for (int yb = 0; yb < 4; ++yb) {
                const float4 wv = *reinterpret_cast<const float4*>(wrow + yb * 64 + sc4);
                #pragma unroll
                for (int i = 0; i < 4; ++i) {
                    o[i][yb][0] = fmaf(sv[i], wv.x, o[i][yb][0]);
                    o[i][yb][1] = fmaf(sv[i], wv.y, o[i][yb][1]);
                    o[i][yb][2] = fmaf(sv[i], wv.z, o[i][yb][2]);
                    o[i][yb][3] = fmaf(sv[i], wv.w, o[i][yb][3]);
                }
            }
        }
        __syncthreads();
    }
    #pragma unroll
    for (int i = 0; i < 4; ++i) {
        const size_t rbase = (size_t)(row0 + pr * 4 + i) * Yd;
        #pragma unroll
        for (int yb = 0; yb < 4; ++yb)
            for (int j = 0; j < 4; ++j)
                atomicAdd(O + rbase + yb * 64 + sc4 + j, o[i][yb][j]);
    }
}

extern "C" void kernel_launch(void* const* d_in, const int* in_sizes, int n_in,
                              void* d_out, int out_size, void* d_ws, size_t ws_size,
                              hipStream_t stream) {
    const float* X = (const float*)d_in[0];   // batch   [8192, 512]
    const float* Z = (const float*)d_in[1];   // centers [8192, 512]
    const float* W = (const float*)d_in[2];   // weight  [8192, 256]
    float* O = (float*)d_out;                 // pred    [8192, 256]

    hipMemsetAsync(d_out, 0, (size_t)out_size * sizeof(float), stream);

    if (ws_size < WS_NEED) {
        dim3 grid(Nn / FBM, FMCH);
        laplace_fused_v1<<<grid, dim3(256), 0, stream>>>(X, Z, W, O);
        return;
    }

    char* ws = (char*)d_ws;
    ushort* Xf  = (ushort*)(ws + OFF_XF);
    ushort* Zf  = (ushort*)(ws + OFF_ZF);
    ushort* Wf  = (ushort*)(ws + OFF_WF);
    float*  xsq = (float*)(ws + OFF_XSQ);
    float*  zsq = (float*)(ws + OFF_ZSQ);

    prep_v10<<<dim3(1024 + 256), dim3(256), 0, stream>>>(
        X, Z, W, Xf, Zf, Wf, xsq, zsq);

    laplace_v10<<<dim3(Nn / BM, MCH), dim3(512), 0, stream>>>(
        Xf, Zf, Wf, xsq, zsq, O);
}

// Round 11
// 216.683 us; speedup vs baseline: 1.1707x; 1.1707x over previous
//
#include <hip/hip_runtime.h>

// Laplacian-kernel regression, fused, bf16 MFMA 16x16x32.
//   d2 = ||x||^2 + ||z||^2 - 2 X.Z^T ; P = exp(-sqrt(d2)/10) ; out = P @ W
// R11: R9/R10 compute + traffic discipline at BM=64 so LDS = 65.8 KB ->
// 2 blocks/CU = two independent barrier domains per CU (R9/R10's 1 block/CU
// phase-locked all 8 waves at each barrier -> ~55% idle, MfmaUtil 23-25%).
//   256 thr / 4 waves, wave grid 1x4; wave = 64x64 (4x4 frags) in QK and PV.
//   X K-halves in LDS (32 KB, 4x reuse); Z/W direct L2 fragment loads;
//   sP 33.8 KB; 4 barriers/m-tile; grid (128,4) = 512 blocks; MCH=4 keeps
//   atomics at 32 MB XCD-local. No manual prefetch (R10 lesson: code bloat,
//   no gain). Cheap transform: rsq-sqrt + exp2 + trunc-bf16.

using frag8 = __attribute__((ext_vector_type(8))) short;   // 8 bf16 (4 VGPRs)
using f32x4 = __attribute__((ext_vector_type(4))) float;   // 16x16 C/D frag

constexpr int Nn = 8192, Mm = 8192, Dd = 512, Yd = 256;
constexpr int BM = 64, BN = 256;
constexpr int MCH = 4, MPER = Mm / MCH, MT = MPER / BN;    // 2048, 8
constexpr int LDP = BN + 8;    // 264 ushort rows (528 B, 16B-aligned)

// Fragment-tile layout: frag(g, c) = rows [16g,16g+16) x k [32c,32c+32),
// 512 ushorts at (g*KG + c)*512, element (r,k) at ushort lane*8 + k%8 where
// lane = r%16 + 16*((k%32)/8).  Xf/Zf: KG=16 (K=512). Wf: rows=y, KG=256.

// workspace layout (bytes)
constexpr size_t OFF_XF  = 0;                               // 8 MB
constexpr size_t OFF_ZF  = OFF_XF + (size_t)Nn * Dd * 2;    // 8 MB
constexpr size_t OFF_WF  = OFF_ZF + (size_t)Mm * Dd * 2;    // 4 MB
constexpr size_t OFF_XSQ = OFF_WF + (size_t)Yd * Mm * 2;
constexpr size_t OFF_ZSQ = OFF_XSQ + (size_t)Nn * 4;
constexpr size_t WS_NEED = OFF_ZSQ + (size_t)Mm * 4;        // ~20.1 MB

__device__ __forceinline__ ushort f2bf(float f) {
    unsigned u = __builtin_bit_cast(unsigned, f);
    u += 0x7FFFu + ((u >> 16) & 1u);          // RNE (prep only)
    return (ushort)(u >> 16);
}

// ---- prep (LDS-tiled, coalesced) ----
__global__ __launch_bounds__(256) void prep_v11(
    const float* __restrict__ X, const float* __restrict__ Z,
    const float* __restrict__ W, ushort* __restrict__ Xf,
    ushort* __restrict__ Zf, ushort* __restrict__ Wf,
    float* __restrict__ xsq, float* __restrict__ zsq)
{
    __shared__ float tile[8320];                  // 16x517 (X/Z) or 32x260 (W)
    __shared__ float part[256];
    const int t = threadIdx.x, b = blockIdx.x;
    if (b < 1024) {
        const int g = (b < 512) ? b : b - 512;
        const float* src = (b < 512 ? X : Z) + (size_t)g * 16 * Dd;
        ushort* dst = (b < 512 ? Xf : Zf) + (size_t)g * 16 * 512;
        float* nrm = (b < 512 ? xsq : zsq) + g * 16;
        #pragma unroll
        for (int rep = 0; rep < 8; ++rep) {       // 2048 float4, coalesced
            const int idx = rep * 256 + t;
            const int r = idx >> 7, c4 = (idx & 127) * 4;
            const float4 v = *(const float4*)(src + (size_t)r * Dd + c4);
            float* d = tile + r * 517 + c4;
            d[0] = v.x; d[1] = v.y; d[2] = v.z; d[3] = v.w;
        }
        __syncthreads();
        {
            const int r = t & 15, s0 = (t >> 4) * 32;
            float sq = 0.0f;
            #pragma unroll
            for (int k = 0; k < 32; ++k) {
                const float v = tile[r * 517 + s0 + k];
                sq += v * v;
            }
            part[t] = sq;
        }
        __syncthreads();
        if (t < 16) {
            float sq = 0.0f;
            #pragma unroll
            for (int s = 0; s < 16; ++s) sq += part[t + 16 * s];
            nrm[t] = sq;
        }
        #pragma unroll
        for (int rep = 0; rep < 4; ++rep) {       // 1024 uint4 frag writes
            const int idx = rep * 256 + t;
            const int kg = idx >> 6, w = idx & 63;
            const int l16 = w & 15, quad = w >> 4;
            const float* s = tile + l16 * 517 + kg * 32 + quad * 8;
            uint4 pk;
            pk.x = (unsigned)f2bf(s[0]) | ((unsigned)f2bf(s[1]) << 16);
            pk.y = (unsigned)f2bf(s[2]) | ((unsigned)f2bf(s[3]) << 16);
            pk.z = (unsigned)f2bf(s[4]) | ((unsigned)f2bf(s[5]) << 16);
            pk.w = (unsigned)f2bf(s[6]) | ((unsigned)f2bf(s[7]) << 16);
            *(uint4*)(dst + (size_t)kg * 512 + w * 8) = pk;
        }
    } else {
        const int zg = b - 1024;                  // 32-z stripe of W
        const float* src = W + (size_t)zg * 32 * Yd;
        #pragma unroll
        for (int rep = 0; rep < 8; ++rep) {
            const int idx = rep * 256 + t;
            const int r = idx >> 6, c4 = (idx & 63) * 4;
            const float4 v = *(const float4*)(src + (size_t)r * Yd + c4);
            float* d = tile + r * 260 + c4;
            d[0] = v.x; d[1] = v.y; d[2] = v.z; d[3] = v.w;
        }
        __syncthreads();
        #pragma unroll
        for (int rep = 0; rep < 4; ++rep) {
            const int idx = rep * 256 + t;
            const int yg = idx >> 6, w = idx & 63;
            const int l16 = w & 15, quad = w >> 4;
            const int y = yg * 16 + l16;
            ushort rr[8];
            #pragma unroll
            for (int j = 0; j < 8; ++j)
                rr[j] = f2bf(tile[(quad * 8 + j) * 260 + y]);
            uint4 pk;
            pk.x = (unsigned)rr[0] | ((unsigned)rr[1] << 16);
            pk.y = (unsigned)rr[2] | ((unsigned)rr[3] << 16);
            pk.z = (unsigned)rr[4] | ((unsigned)rr[5] << 16);
            pk.w = (unsigned)rr[6] | ((unsigned)rr[7] << 16);
            *(uint4*)(Wf + ((size_t)yg * 256 + zg) * 512 + w * 8) = pk;
        }
    }
}

// ---- main fused kernel ----
__global__ __launch_bounds__(256, 2) void laplace_v11(
    const ushort* __restrict__ Xf, const ushort* __restrict__ Zf,
    const ushort* __restrict__ Wf, const float* __restrict__ xsqg,
    const float* __restrict__ zsqg, float* __restrict__ O)
{
    __shared__ ushort sXh[32 * 512];              // 32 KB: X K-half (32 frags)
    __shared__ ushort sP[BM * LDP];               // 33.8 KB
    const int t = threadIdx.x, wid = t >> 6, lane = t & 63;
    const int l16 = lane & 15, quad = lane >> 4;
    const int row0  = blockIdx.x * BM;            // XCD = blockIdx.x % 8
    const int zbase = blockIdx.y * MPER;
    const int xg0 = row0 >> 4;                    // X 16-row-group base

    float xs[4][4];
    #pragma unroll
    for (int i = 0; i < 4; ++i)
        #pragma unroll
        for (int r = 0; r < 4; ++r)
            xs[i][r] = xsqg[row0 + 16 * i + quad * 4 + r];

    f32x4 Oa[4][4];
    #pragma unroll
    for (int i = 0; i < 4; ++i)
        #pragma unroll
        for (int j = 0; j < 4; ++j)
            #pragma unroll
            for (int r = 0; r < 4; ++r) Oa[i][j][r] = 0.0f;

    // wave-contiguous staging pointers: wave wid stages row-group (xg0+wid),
    // 8 k-groups per half
    const ushort* xsrc = Xf + ((size_t)(xg0 + wid) * 16) * 512 + lane * 8;
    ushort* xdst = sXh + wid * 8 * 512 + lane * 8;

    for (int mt = 0; mt < MT; ++mt) {
        const int zg0 = (zbase >> 4) + mt * 16;
        float zs4[4];
        #pragma unroll
        for (int j = 0; j < 4; ++j)
            zs4[j] = zsqg[zbase + mt * 256 + wid * 64 + 16 * j + l16];

        f32x4 S[4][4];
        #pragma unroll
        for (int i = 0; i < 4; ++i)
            #pragma unroll
            for (int j = 0; j < 4; ++j)
                #pragma unroll
                for (int r = 0; r < 4; ++r) S[i][j][r] = 0.0f;

        const unsigned zo0 = (unsigned)(zg0 + wid * 4) * 8192u + lane * 8;

        // ---- QK in two K-halves; X from LDS (4x reuse), Z direct ----
        #pragma unroll
        for (int h = 0; h < 2; ++h) {
            #pragma unroll
            for (int c = 0; c < 8; ++c)           // 8 x 1KB per wave
                *(uint4*)(xdst + c * 512) =
                    *(const uint4*)(xsrc + (size_t)(h * 8 + c) * 512);
            __syncthreads();                      // sXh ready
            const unsigned zoh = zo0 + h * 4096u;
            #pragma unroll
            for (int kk = 0; kk < 8; ++kk) {
                frag8 a[4], b[4];
                #pragma unroll
                for (int j = 0; j < 4; ++j)
                    b[j] = *(const frag8*)(Zf + zoh + kk * 512u + j * 8192u);
                #pragma unroll
                for (int i = 0; i < 4; ++i)
                    a[i] = *(const frag8*)(sXh + (i * 8 + kk) * 512 + lane * 8);
                #pragma unroll
                for (int i = 0; i < 4; ++i)
                    #pragma unroll
                    for (int j = 0; j < 4; ++j)
                        S[i][j] = __builtin_amdgcn_mfma_f32_16x16x32_bf16(
                            a[i], b[j], S[i][j], 0, 0, 0);
            }
            if (h == 0) __syncthreads();          // h0 sXh reads done
        }

        // ---- transform -> sP (C/D: col=l16, row=quad*4+r) ----
        #pragma unroll
        for (int i = 0; i < 4; ++i) {
            const int xl = 16 * i + quad * 4;
            #pragma unroll
            for (int j = 0; j < 4; ++j) {
                const int col = wid * 64 + 16 * j + l16;
                const float zz = zs4[j];
                #pragma unroll
                for (int r = 0; r < 4; ++r) {
                    const float xpz = xs[i][r] + zz;
                    float d2 = fmaf(S[i][j][r], -2.0f, xpz);
                    d2 = fmaxf(d2, 1e-20f);
                    const float dist = d2 * __frsqrt_rn(d2);     // sqrt(d2)
                    const float e = __builtin_amdgcn_exp2f(
                        dist * -0.14426950408889634f);           // exp(-dist/10)
                    sP[(xl + r) * LDP + col] =
                        (ushort)(__builtin_bit_cast(unsigned, e) >> 16);
                }
            }
        }
        __syncthreads();                          // sP visible

        // ---- PV: O += P[64x256].W[256x256]; A from sP, B direct ----
        const unsigned wo0 = (unsigned)(wid * 4) * 131072u +
                             (unsigned)((zbase >> 5) + mt * 8) * 512u + lane * 8;
        #pragma unroll
        for (int pv = 0; pv < 8; ++pv) {
            frag8 ap[4], bw[4];
            #pragma unroll
            for (int j = 0; j < 4; ++j)
                bw[j] = *(const frag8*)(Wf + wo0 + pv * 512u + j * 131072u);
            #pragma unroll
            for (int i = 0; i < 4; ++i)
                ap[i] = *(const frag8*)(
                    sP + (16 * i + l16) * LDP + pv * 32 + quad * 8);
            #pragma unroll
            for (int j = 0; j < 4; ++j)
                #pragma unroll
                for (int i = 0; i < 4; ++i)
                    Oa[i][j] = __builtin_amdgcn_mfma_f32_16x16x32_bf16(
                        ap[i], bw[j], Oa[i][j], 0, 0, 0);
        }
        // next mt's h0 restage is safe: sP barrier implies h1 reads done.
    }

    // ---- epilogue: combine MCH=4 chunks via fp32 atomics (XCD-local) ----
    #pragma unroll
    for (int i = 0; i < 4; ++i) {
        const int xr = row0 + 16 * i + quad * 4;
        #pragma unroll
        for (int j = 0; j < 4; ++j) {
            const int col = wid * 64 + 16 * j + l16;
            #pragma unroll
            for (int r = 0; r < 4; ++r)
                atomicAdd(&O[(size_t)(xr + r) * Yd + col], Oa[i][j][r]);
        }
    }
}

// ---- fallback (fp32 VALU fused kernel) if workspace is too small ----
constexpr int FBM = 64, FBN = 64, FBK = 64;
constexpr int FMCH = 4, FMCHUNK = Mm / FMCH, FMSTEPS = FMCHUNK / FBN, FDSTEPS = Dd / FBK;
constexpr int FLDA = FBK + 1, FLDSS = FBN + 1;

__global__ __launch_bounds__(256, 3) void laplace_fused_v1(
    const float* __restrict__ X, const float* __restrict__ Z,
    const float* __restrict__ W, float* __restrict__ O)
{
    __shared__ float sX[FBM * FLDA];
    __shared__ float sZ[FBN * FLDA];
    __shared__ float sS[FBM * FLDSS];
    const int t = threadIdx.x, pr = t >> 4, pc = t & 15, sc4 = pc * 4;
    const int row0 = blockIdx.x * FBM, mbase = blockIdx.y * FMCHUNK;
    float o[4][4][4];
    #pragma unroll
    for (int i = 0; i < 4; ++i)
        for (int yb = 0; yb < 4; ++yb)
            for (int j = 0; j < 4; ++j) o[i][yb][j] = 0.0f;
    for (int ms = 0; ms < FMSTEPS; ++ms) {
        const int zrow0 = mbase + ms * FBN;
        float s[4][4];
        #pragma unroll
        for (int i = 0; i < 4; ++i)
            for (int j = 0; j < 4; ++j) s[i][j] = 0.0f;
        for (int kk = 0; kk < FDSTEPS; ++kk) {
            const int k0 = kk * FBK;
            __syncthreads();
            #pragma unroll
            for (int rep = 0; rep < 4; ++rep) {
                const int r = pr + rep * 16;
                const float4 xv = *reinterpret_cast<const float4*>(X + (size_t)(row0 + r) * Dd + k0 + sc4);
                const float4 zv = *reinterpret_cast<const float4*>(Z + (size_t)(zrow0 + r) * Dd + k0 + sc4);
                float* dx = sX + r * FLDA + sc4;
                dx[0] = xv.x; dx[1] = xv.y; dx[2] = xv.z; dx[3] = xv.w;
                float* dz = sZ + r * FLDA + sc4;
                dz[0] = zv.x; dz[1] = zv.y; dz[2] = zv.z; dz[3] = zv.w;
            }
            __syncthreads();
            #pragma unroll 4
            for (int k = 0; k < FBK; ++k) {
                float xr[4], zc[4];
                #pragma unroll
                for (int i = 0; i < 4; ++i) xr[i] = sX[(pr * 4 + i) * FLDA + k];
                #pragma unroll
                for (int j = 0; j < 4; ++j) zc[j] = sZ[(pc * 4 + j) * FLDA + k];
                #pragma unroll
                for (int i = 0; i < 4; ++i)
                    #pragma unroll
                    for (int j = 0; j < 4; ++j) {
                        const float d = xr[i] - zc[j];
                        s[i][j] = fmaf(d, d, s[i][j]);
                    }
            }
        }
        #pragma unroll
        for (int i = 0; i < 4; ++i)
            for (int j = 0; j < 4; ++j)
                sS[(pr * 4 + i) * FLDSS + sc4 + j] = __expf(-sqrtf(s[i][j]) * 0.1f);
        __syncthreads();
        #pragma unroll 2
        for (int c = 0; c < FBN; ++c) {
            float sv[4];
            #pragma unroll
            for (int i = 0; i < 4; ++i) sv[i] = sS[(pr * 4 + i) * FLDSS + c];
            const float* wrow = W + (size_t)(zrow0 + c) * Yd;
            #pragma unroll
            for (int yb = 0; yb < 4; ++yb) {
                const float4 wv = *reinterpret_cast<const float4*>(wrow + yb * 64 + sc4);
                #pragma unroll
                for (int i = 0; i < 4; ++i) {
                    o[i][yb][0] = fmaf(sv[i], wv.x, o[i][yb][0]);
                    o[i][yb][1] = fmaf(sv[i], wv.y, o[i][yb][1]);
                    o[i][yb][2] = fmaf(sv[i], wv.z, o[i][yb][2]);
                    o[i][yb][3] = fmaf(sv[i], wv.w, o[i][yb][3]);
                }
            }
        }
        __syncthreads();
    }
    #pragma unroll
    for (int i = 0; i < 4; ++i) {
        const size_t rbase = (size_t)(row0 + pr * 4 + i) * Yd;
        #pragma unroll
        for (int yb = 0; yb < 4; ++yb)
            for (int j = 0; j < 4; ++j)
                atomicAdd(O + rbase + yb * 64 + sc4 + j, o[i][yb][j]);
    }
}

extern "C" void kernel_launch(void* const* d_in, const int* in_sizes, int n_in,
                              void* d_out, int out_size, void* d_ws, size_t ws_size,
                              hipStream_t stream) {
    const float* X = (const float*)d_in[0];   // batch   [8192, 512]
    const float* Z = (const float*)d_in[1];   // centers [8192, 512]
    const float* W = (const float*)d_in[2];   // weight  [8192, 256]
    float* O = (float*)d_out;                 // pred    [8192, 256]

    hipMemsetAsync(d_out, 0, (size_t)out_size * sizeof(float), stream);

    if (ws_size < WS_NEED) {
        dim3 grid(Nn / FBM, FMCH);
        laplace_fused_v1<<<grid, dim3(256), 0, stream>>>(X, Z, W, O);
        return;
    }

    char* ws = (char*)d_ws;
    ushort* Xf  = (ushort*)(ws + OFF_XF);
    ushort* Zf  = (ushort*)(ws + OFF_ZF);
    ushort* Wf  = (ushort*)(ws + OFF_WF);
    float*  xsq = (float*)(ws + OFF_XSQ);
    float*  zsq = (float*)(ws + OFF_ZSQ);

    prep_v11<<<dim3(1024 + 256), dim3(256), 0, stream>>>(
        X, Z, W, Xf, Zf, Wf, xsq, zsq);

    laplace_v11<<<dim3(Nn / BM, MCH), dim3(256), 0, stream>>>(
        Xf, Zf, Wf, xsq, zsq, O);
}